// Round 13
// baseline (105.872 us; speedup 1.0000x reference)
//
#include <hip/hip_runtime.h>
#include <hip/hip_bf16.h>

#define NNODES 100000
#define NEDGES 1600000
#define IN_C   256
#define OUT_C  128

typedef short bf16x8 __attribute__((ext_vector_type(8)));
typedef float f32x4  __attribute__((ext_vector_type(4)));

static __device__ __forceinline__ unsigned short f2bf(float f) {
    union { float f; unsigned u; } c; c.f = f;
    unsigned r = c.u + 0x7fffu + ((c.u >> 16) & 1u);   // round-to-nearest-even
    return (unsigned short)(r >> 16);
}

union BF8 { bf16x8 v; unsigned short s[8]; };

// ---------------------------------------------------------------------------
// GEMM: H8(biased uint8, row-major, per-row scale) = quant(X @ W^T).
// (unchanged from round 12: W in 64KB swizzled LDS, X direct to A-frags,
//  barrier-free K-loop, per-row amax -> q+128 uint8.)
// ---------------------------------------------------------------------------
__global__ __launch_bounds__(512, 4) void gemm_xwt(const float* __restrict__ X,
                                                   const float* __restrict__ W,
                                                   unsigned char* __restrict__ H8,
                                                   float* __restrict__ scale) {
    __shared__ unsigned short Wsh[128 * 256];   // bf16 bits, [n][k], swizzled, 64KB

    const int tid  = threadIdx.x;
    const int lane = tid & 63;
    const int wid  = tid >> 6;                  // 0..7

#pragma unroll
    for (int p = 0; p < 16; ++p) {
        int idx = p * 512 + tid;                // 0..8191 float4 index
        int n   = idx >> 6;                     // 0..127
        int c4  = idx & 63;                     // float4 column
        float4 v = *(const float4*)(W + (size_t)n * IN_C + c4 * 4);
        int byte = (n * 512 + c4 * 8) ^ ((n & 7) << 4);
        *(ushort4*)((char*)Wsh + byte) =
            make_ushort4(f2bf(v.x), f2bf(v.y), f2bf(v.z), f2bf(v.w));
    }
    __syncthreads();

    const int r0   = blockIdx.x * 128 + wid * 16;
    int arow = r0 + (lane & 15);
    if (arow > NNODES - 1) arow = NNODES - 1;   // clamp (tail rows discarded)
    const float* xrow = X + (size_t)arow * IN_C + (lane >> 4) * 8;

    f32x4 acc[8] = {};
#pragma unroll
    for (int ks = 0; ks < 8; ++ks) {
        float4 a0 = *(const float4*)(xrow + ks * 32);
        float4 a1 = *(const float4*)(xrow + ks * 32 + 4);
        BF8 t;
        t.s[0] = f2bf(a0.x); t.s[1] = f2bf(a0.y); t.s[2] = f2bf(a0.z); t.s[3] = f2bf(a0.w);
        t.s[4] = f2bf(a1.x); t.s[5] = f2bf(a1.y); t.s[6] = f2bf(a1.z); t.s[7] = f2bf(a1.w);
        const int kb = ks * 64 + (lane >> 4) * 16;      // byte offset in W row
#pragma unroll
        for (int n8 = 0; n8 < 8; ++n8) {
            int nr   = n8 * 16 + (lane & 15);
            int byte = (nr * 512 + kb) ^ ((nr & 7) << 4);
            bf16x8 b = *(const bf16x8*)((const char*)Wsh + byte);
            acc[n8] = __builtin_amdgcn_mfma_f32_16x16x32_bf16(t.v, b, acc[n8],
                                                              0, 0, 0);
        }
    }

    // --- epilogue: per-row amax -> biased-uint8 quantize (row-major) ---
    float amax[4];
#pragma unroll
    for (int r = 0; r < 4; ++r) {
        float m = 0.f;
#pragma unroll
        for (int n8 = 0; n8 < 8; ++n8) m = fmaxf(m, fabsf(acc[n8][r]));
        amax[r] = m;
    }
#pragma unroll
    for (int d = 1; d < 16; d <<= 1)
#pragma unroll
        for (int r = 0; r < 4; ++r)
            amax[r] = fmaxf(amax[r], __shfl_xor(amax[r], d));

#pragma unroll
    for (int r = 0; r < 4; ++r) {
        int grow = r0 + (lane >> 4) * 4 + r;
        if (grow < NNODES) {
            float am  = amax[r];
            float inv = am > 0.f ? 127.f / am : 0.f;
            if ((lane & 15) == 0) scale[grow] = am * (1.f / 127.f);
#pragma unroll
            for (int n8 = 0; n8 < 8; ++n8) {
                float q = rintf(acc[n8][r] * inv);
                q = fminf(127.f, fmaxf(-127.f, q));
                H8[(size_t)grow * OUT_C + n8 * 16 + (lane & 15)] =
                    (unsigned char)((int)q + 128);
            }
        }
    }
}

// ---------------------------------------------------------------------------
// rowptr[r] = lower_bound(A_rows, r)  (A_rows sorted).  r in [0, N].
// ---------------------------------------------------------------------------
__global__ __launch_bounds__(256) void build_rowptr(const int* __restrict__ rows,
                                                    int* __restrict__ rowptr) {
    int r = blockIdx.x * 256 + threadIdx.x;
    if (r > NNODES) return;
    int lo = 0, hi = NEDGES;
    while (lo < hi) {
        int mid = (lo + hi) >> 1;
        if (rows[mid] < r) lo = mid + 1; else hi = mid;
    }
    rowptr[r] = lo;
}

// ---------------------------------------------------------------------------
// SpMM: out[r,:] = sum_e vals[e]*scale[c_e] * H8[c_e,:].
// 8 LANES PER EDGE, uint4 gathers: int8 row = 128B = 8 x 16B -> 8 gather
// addresses per edge (halved vs all prior rounds). Lane holds 16 channels.
// Two-row pipeline (round-10, best measured); 64-edge shfl preload;
// wave-uniform guards; 4 x 8-edge gathers (32 edges) in flight per iter.
// Biased-uint8 unpack (v_cvt_f32_ubyteN); exact -128*sum(w) correction after
// the 3-level cross-group reduce. Lanes 0-7 store 512B contiguous (NT).
// ---------------------------------------------------------------------------
static __device__ __forceinline__ void fma16(float acc[16], float* sw,
                                             uint4 u, float v) {
    *sw += v;
#pragma unroll
    for (int d = 0; d < 4; ++d) {
        unsigned ud = (&u.x)[d];
        acc[d * 4 + 0] += v * (float)( ud        & 0xffu);
        acc[d * 4 + 1] += v * (float)((ud >>  8) & 0xffu);
        acc[d * 4 + 2] += v * (float)((ud >> 16) & 0xffu);
        acc[d * 4 + 3] += v * (float)( ud >> 24);
    }
}

__global__ __launch_bounds__(256) void spmm_rows(const uint4* __restrict__ H4,
                                                 const int* __restrict__ rowptr,
                                                 const int* __restrict__ cols,
                                                 const float* __restrict__ vals,
                                                 const float* __restrict__ scale,
                                                 float* __restrict__ out) {
    const int wid  = threadIdx.x >> 6;
    const int lane = threadIdx.x & 63;
    const int g    = lane >> 3;      // edge subgroup 0..7
    const int cg   = lane & 7;       // 16B slot -> channels cg*16 .. cg*16+15

    const int rowA = (blockIdx.x * 4 + wid) * 2;   // rowB = rowA + 1
    const int sA = rowptr[rowA];
    const int eA = rowptr[rowA + 1];
    const int eB = rowptr[rowA + 2];

    float accA[16], accB[16];
#pragma unroll
    for (int t = 0; t < 16; ++t) { accA[t] = 0.f; accB[t] = 0.f; }
    float swA = 0.f, swB = 0.f;

    int baseA = sA, baseB = eA;
    while (baseA < eA || baseB < eB) {
        int cntA = eA - baseA; cntA = cntA < 0 ? 0 : (cntA > 64 ? 64 : cntA);
        int cntB = eB - baseB; cntB = cntB < 0 ? 0 : (cntB > 64 ? 64 : cntB);

        int   ecA = 0, ecB = 0;
        float evA = 0.f, evB = 0.f;
        if (lane < cntA) { ecA = cols[baseA + lane]; evA = vals[baseA + lane] * scale[ecA]; }
        if (lane < cntB) { ecB = cols[baseB + lane]; evB = vals[baseB + lane] * scale[ecB]; }

        const int mx = cntA > cntB ? cntA : cntB;
        for (int j = 0; j < mx; j += 16) {
            const bool dA0 = j < cntA, dA1 = j + 8 < cntA;
            const bool dB0 = j < cntB, dB1 = j + 8 < cntB;

            uint4 uA0, uA1, uB0, uB1;
            float vA0, vA1, vB0, vB1;
            // issue phase: 4 gathers (32 edges) back-to-back
            if (dA0) { int c = __shfl(ecA, j + g);     vA0 = __shfl(evA, j + g);
                       uA0 = H4[(size_t)c * 8 + cg]; }
            if (dB0) { int c = __shfl(ecB, j + g);     vB0 = __shfl(evB, j + g);
                       uB0 = H4[(size_t)c * 8 + cg]; }
            if (dA1) { int c = __shfl(ecA, j + 8 + g); vA1 = __shfl(evA, j + 8 + g);
                       uA1 = H4[(size_t)c * 8 + cg]; }
            if (dB1) { int c = __shfl(ecB, j + 8 + g); vB1 = __shfl(evB, j + 8 + g);
                       uB1 = H4[(size_t)c * 8 + cg]; }
            // consume phase (issue order)
            if (dA0) fma16(accA, &swA, uA0, vA0);
            if (dB0) fma16(accB, &swB, uB0, vB0);
            if (dA1) fma16(accA, &swA, uA1, vA1);
            if (dB1) fma16(accB, &swB, uB1, vB1);
        }

        baseA += cntA;
        baseB += cntB;
    }

    // reduce across the 8 edge subgroups, then exact bias correction
#pragma unroll
    for (int t = 0; t < 16; ++t) {
        accA[t] += __shfl_xor(accA[t], 8);
        accA[t] += __shfl_xor(accA[t], 16);
        accA[t] += __shfl_xor(accA[t], 32);
        accB[t] += __shfl_xor(accB[t], 8);
        accB[t] += __shfl_xor(accB[t], 16);
        accB[t] += __shfl_xor(accB[t], 32);
    }
    swA += __shfl_xor(swA, 8); swA += __shfl_xor(swA, 16); swA += __shfl_xor(swA, 32);
    swB += __shfl_xor(swB, 8); swB += __shfl_xor(swB, 16); swB += __shfl_xor(swB, 32);

    if (lane < 8) {
        const float bA = 128.f * swA, bB = 128.f * swB;
        float* oA = out + (size_t)rowA * OUT_C + cg * 16;
        float* oB = out + (size_t)(rowA + 1) * OUT_C + cg * 16;
#pragma unroll
        for (int q = 0; q < 4; ++q) {
            f32x4 va = { accA[q * 4 + 0] - bA, accA[q * 4 + 1] - bA,
                         accA[q * 4 + 2] - bA, accA[q * 4 + 3] - bA };
            f32x4 vb = { accB[q * 4 + 0] - bB, accB[q * 4 + 1] - bB,
                         accB[q * 4 + 2] - bB, accB[q * 4 + 3] - bB };
            __builtin_nontemporal_store(va, (f32x4*)(oA + q * 4));
            __builtin_nontemporal_store(vb, (f32x4*)(oB + q * 4));
        }
    }
}

// ---------------------------------------------------------------------------
extern "C" void kernel_launch(void* const* d_in, const int* in_sizes, int n_in,
                              void* d_out, int out_size, void* d_ws, size_t ws_size,
                              hipStream_t stream) {
    const float* X      = (const float*)d_in[0];
    const float* W      = (const float*)d_in[1];
    const int*   A_rows = (const int*)d_in[2];
    const int*   A_cols = (const int*)d_in[3];
    const float* A_vals = (const float*)d_in[4];
    float* out = (float*)d_out;

    unsigned char* H8    = (unsigned char*)d_ws;                        // 12.8 MB
    float*         scale = (float*)((char*)d_ws + (size_t)NNODES * OUT_C); // 400 KB
    int*           rowptr = (int*)((char*)scale + (size_t)NNODES * sizeof(float));

    gemm_xwt<<<(NNODES + 127) / 128, 512, 0, stream>>>(X, W, H8, scale);
    build_rowptr<<<(NNODES + 1 + 255) / 256, 256, 0, stream>>>(A_rows, rowptr);
    spmm_rows<<<(NNODES + 7) / 8, 256, 0, stream>>>((const uint4*)H8, rowptr,
                                                    A_cols, A_vals, scale, out);
}

// Round 14
// 104.135 us; speedup vs baseline: 1.0167x; 1.0167x over previous
//
#include <hip/hip_runtime.h>
#include <hip/hip_bf16.h>

#define NNODES 100000
#define NEDGES 1600000
#define IN_C   256
#define OUT_C  128

typedef short bf16x8 __attribute__((ext_vector_type(8)));
typedef float f32x4  __attribute__((ext_vector_type(4)));

static __device__ __forceinline__ unsigned short f2bf(float f) {
    union { float f; unsigned u; } c; c.f = f;
    unsigned r = c.u + 0x7fffu + ((c.u >> 16) & 1u);   // round-to-nearest-even
    return (unsigned short)(r >> 16);
}

union BF8 { bf16x8 v; unsigned short s[8]; };

// ---------------------------------------------------------------------------
// GEMM: H8(biased uint8, row-major, per-row scale) = quant(X @ W^T).
// W in 64KB swizzled LDS, X direct to A-frags (barrier-free K-loop)
// + EXPLICIT ks+1 PREFETCH of the X float4 pair (doubles in-flight loads;
//   un-prefetched version measured ~3.8 TB/s on X vs 6.3 achievable).
// ---------------------------------------------------------------------------
__global__ __launch_bounds__(512, 4) void gemm_xwt(const float* __restrict__ X,
                                                   const float* __restrict__ W,
                                                   unsigned char* __restrict__ H8,
                                                   float* __restrict__ scale) {
    __shared__ unsigned short Wsh[128 * 256];   // bf16 bits, [n][k], swizzled, 64KB

    const int tid  = threadIdx.x;
    const int lane = tid & 63;
    const int wid  = tid >> 6;                  // 0..7

#pragma unroll
    for (int p = 0; p < 16; ++p) {
        int idx = p * 512 + tid;                // 0..8191 float4 index
        int n   = idx >> 6;                     // 0..127
        int c4  = idx & 63;                     // float4 column
        float4 v = *(const float4*)(W + (size_t)n * IN_C + c4 * 4);
        int byte = (n * 512 + c4 * 8) ^ ((n & 7) << 4);
        *(ushort4*)((char*)Wsh + byte) =
            make_ushort4(f2bf(v.x), f2bf(v.y), f2bf(v.z), f2bf(v.w));
    }
    __syncthreads();

    const int r0   = blockIdx.x * 128 + wid * 16;
    int arow = r0 + (lane & 15);
    if (arow > NNODES - 1) arow = NNODES - 1;   // clamp (tail rows discarded)
    const float* xrow = X + (size_t)arow * IN_C + (lane >> 4) * 8;

    f32x4 acc[8] = {};
    float4 a0 = *(const float4*)(xrow);
    float4 a1 = *(const float4*)(xrow + 4);
#pragma unroll
    for (int ks = 0; ks < 8; ++ks) {
        float4 n0, n1;
        if (ks < 7) {                            // prefetch next k-slice
            n0 = *(const float4*)(xrow + (ks + 1) * 32);
            n1 = *(const float4*)(xrow + (ks + 1) * 32 + 4);
        }
        BF8 t;
        t.s[0] = f2bf(a0.x); t.s[1] = f2bf(a0.y); t.s[2] = f2bf(a0.z); t.s[3] = f2bf(a0.w);
        t.s[4] = f2bf(a1.x); t.s[5] = f2bf(a1.y); t.s[6] = f2bf(a1.z); t.s[7] = f2bf(a1.w);
        const int kb = ks * 64 + (lane >> 4) * 16;      // byte offset in W row
#pragma unroll
        for (int n8 = 0; n8 < 8; ++n8) {
            int nr   = n8 * 16 + (lane & 15);
            int byte = (nr * 512 + kb) ^ ((nr & 7) << 4);
            bf16x8 b = *(const bf16x8*)((const char*)Wsh + byte);
            acc[n8] = __builtin_amdgcn_mfma_f32_16x16x32_bf16(t.v, b, acc[n8],
                                                              0, 0, 0);
        }
        if (ks < 7) { a0 = n0; a1 = n1; }
    }

    // --- epilogue: per-row amax -> biased-uint8 quantize (row-major) ---
    float amax[4];
#pragma unroll
    for (int r = 0; r < 4; ++r) {
        float m = 0.f;
#pragma unroll
        for (int n8 = 0; n8 < 8; ++n8) m = fmaxf(m, fabsf(acc[n8][r]));
        amax[r] = m;
    }
#pragma unroll
    for (int d = 1; d < 16; d <<= 1)
#pragma unroll
        for (int r = 0; r < 4; ++r)
            amax[r] = fmaxf(amax[r], __shfl_xor(amax[r], d));

#pragma unroll
    for (int r = 0; r < 4; ++r) {
        int grow = r0 + (lane >> 4) * 4 + r;
        if (grow < NNODES) {
            float am  = amax[r];
            float inv = am > 0.f ? 127.f / am : 0.f;
            if ((lane & 15) == 0) scale[grow] = am * (1.f / 127.f);
#pragma unroll
            for (int n8 = 0; n8 < 8; ++n8) {
                float q = rintf(acc[n8][r] * inv);
                q = fminf(127.f, fmaxf(-127.f, q));
                H8[(size_t)grow * OUT_C + n8 * 16 + (lane & 15)] =
                    (unsigned char)((int)q + 128);
            }
        }
    }
}

// ---------------------------------------------------------------------------
// rowptr[r] = lower_bound(A_rows, r)  (A_rows sorted).  r in [0, N].
// ---------------------------------------------------------------------------
__global__ __launch_bounds__(256) void build_rowptr(const int* __restrict__ rows,
                                                    int* __restrict__ rowptr) {
    int r = blockIdx.x * 256 + threadIdx.x;
    if (r > NNODES) return;
    int lo = 0, hi = NEDGES;
    while (lo < hi) {
        int mid = (lo + hi) >> 1;
        if (rows[mid] < r) lo = mid + 1; else hi = mid;
    }
    rowptr[r] = lo;
}

// ---------------------------------------------------------------------------
// SpMM: out[r,:] = sum_e vals[e]*scale[c_e] * H8[c_e,:].
// FOUR rows per wave (R10's 2-row pipeline extended — the only lever with a
// positive measurement): 4 independent {preload, gather, acc} chains
// interleaved, 8 uint2 gathers in flight. 16 lanes/edge, R10's exact inner
// pattern; wave-uniform guards. Biased-uint8 unpack + exact -128*sum(w)
// correction after the cross-group reduce. NT out stores.
// ---------------------------------------------------------------------------
static __device__ __forceinline__ void edge4u(float acc[8], float* sw,
                                              int ec, float ev, int jg,
                                              const uint2* __restrict__ H2,
                                              int cg) {
    int   c = __shfl(ec, jg);
    float v = __shfl(ev, jg);
    uint2 u = H2[(size_t)c * 16 + cg];
    *sw += v;
    acc[0] += v * (float)( u.x        & 0xffu);
    acc[1] += v * (float)((u.x >>  8) & 0xffu);
    acc[2] += v * (float)((u.x >> 16) & 0xffu);
    acc[3] += v * (float)( u.x >> 24);
    acc[4] += v * (float)( u.y        & 0xffu);
    acc[5] += v * (float)((u.y >>  8) & 0xffu);
    acc[6] += v * (float)((u.y >> 16) & 0xffu);
    acc[7] += v * (float)( u.y >> 24);
}

__global__ __launch_bounds__(256) void spmm_rows(const uint2* __restrict__ H2,
                                                 const int* __restrict__ rowptr,
                                                 const int* __restrict__ cols,
                                                 const float* __restrict__ vals,
                                                 const float* __restrict__ scale,
                                                 float* __restrict__ out) {
    const int wid  = threadIdx.x >> 6;
    const int lane = threadIdx.x & 63;
    const int g    = lane >> 4;      // edge subgroup 0..3
    const int cg   = lane & 15;      // channel group: channels cg*8 .. cg*8+7

    const int rowA = (blockIdx.x * 4 + wid) * 4;   // rows rowA .. rowA+3
    const int p0 = rowptr[rowA];
    const int p1 = rowptr[rowA + 1];
    const int p2 = rowptr[rowA + 2];
    const int p3 = rowptr[rowA + 3];
    const int p4 = rowptr[rowA + 4];

    float accA[8], accB[8], accC[8], accD[8];
#pragma unroll
    for (int t = 0; t < 8; ++t) { accA[t] = 0.f; accB[t] = 0.f;
                                  accC[t] = 0.f; accD[t] = 0.f; }
    float swA = 0.f, swB = 0.f, swC = 0.f, swD = 0.f;

    int baseA = p0, baseB = p1, baseC = p2, baseD = p3;
    while (baseA < p1 || baseB < p2 || baseC < p3 || baseD < p4) {
        int cntA = p1 - baseA; cntA = cntA < 0 ? 0 : (cntA > 64 ? 64 : cntA);
        int cntB = p2 - baseB; cntB = cntB < 0 ? 0 : (cntB > 64 ? 64 : cntB);
        int cntC = p3 - baseC; cntC = cntC < 0 ? 0 : (cntC > 64 ? 64 : cntC);
        int cntD = p4 - baseD; cntD = cntD < 0 ? 0 : (cntD > 64 ? 64 : cntD);

        int   ecA = 0, ecB = 0, ecC = 0, ecD = 0;
        float evA = 0.f, evB = 0.f, evC = 0.f, evD = 0.f;
        if (lane < cntA) { ecA = cols[baseA + lane]; evA = vals[baseA + lane] * scale[ecA]; }
        if (lane < cntB) { ecB = cols[baseB + lane]; evB = vals[baseB + lane] * scale[ecB]; }
        if (lane < cntC) { ecC = cols[baseC + lane]; evC = vals[baseC + lane] * scale[ecC]; }
        if (lane < cntD) { ecD = cols[baseD + lane]; evD = vals[baseD + lane] * scale[ecD]; }

        int mx = cntA > cntB ? cntA : cntB;
        mx = mx > cntC ? mx : cntC;
        mx = mx > cntD ? mx : cntD;
        for (int j = 0; j < mx; j += 8) {
            if (j < cntA)     edge4u(accA, &swA, ecA, evA, j + g,     H2, cg);
            if (j < cntB)     edge4u(accB, &swB, ecB, evB, j + g,     H2, cg);
            if (j < cntC)     edge4u(accC, &swC, ecC, evC, j + g,     H2, cg);
            if (j < cntD)     edge4u(accD, &swD, ecD, evD, j + g,     H2, cg);
            if (j + 4 < cntA) edge4u(accA, &swA, ecA, evA, j + 4 + g, H2, cg);
            if (j + 4 < cntB) edge4u(accB, &swB, ecB, evB, j + 4 + g, H2, cg);
            if (j + 4 < cntC) edge4u(accC, &swC, ecC, evC, j + 4 + g, H2, cg);
            if (j + 4 < cntD) edge4u(accD, &swD, ecD, evD, j + 4 + g, H2, cg);
        }

        baseA += cntA; baseB += cntB; baseC += cntC; baseD += cntD;
    }

    // reduce across the 4 edge subgroups, then exact bias correction
#pragma unroll
    for (int t = 0; t < 8; ++t) {
        accA[t] += __shfl_xor(accA[t], 16); accA[t] += __shfl_xor(accA[t], 32);
        accB[t] += __shfl_xor(accB[t], 16); accB[t] += __shfl_xor(accB[t], 32);
        accC[t] += __shfl_xor(accC[t], 16); accC[t] += __shfl_xor(accC[t], 32);
        accD[t] += __shfl_xor(accD[t], 16); accD[t] += __shfl_xor(accD[t], 32);
    }
    swA += __shfl_xor(swA, 16); swA += __shfl_xor(swA, 32);
    swB += __shfl_xor(swB, 16); swB += __shfl_xor(swB, 32);
    swC += __shfl_xor(swC, 16); swC += __shfl_xor(swC, 32);
    swD += __shfl_xor(swD, 16); swD += __shfl_xor(swD, 32);

    if (lane < 16) {
        const float bA = 128.f * swA, bB = 128.f * swB;
        const float bC = 128.f * swC, bD = 128.f * swD;
        f32x4 a0 = { accA[0] - bA, accA[1] - bA, accA[2] - bA, accA[3] - bA };
        f32x4 a1 = { accA[4] - bA, accA[5] - bA, accA[6] - bA, accA[7] - bA };
        f32x4 b0 = { accB[0] - bB, accB[1] - bB, accB[2] - bB, accB[3] - bB };
        f32x4 b1 = { accB[4] - bB, accB[5] - bB, accB[6] - bB, accB[7] - bB };
        f32x4 c0 = { accC[0] - bC, accC[1] - bC, accC[2] - bC, accC[3] - bC };
        f32x4 c1 = { accC[4] - bC, accC[5] - bC, accC[6] - bC, accC[7] - bC };
        f32x4 d0 = { accD[0] - bD, accD[1] - bD, accD[2] - bD, accD[3] - bD };
        f32x4 d1 = { accD[4] - bD, accD[5] - bD, accD[6] - bD, accD[7] - bD };
        float* o = out + (size_t)rowA * OUT_C + cg * 8;
        __builtin_nontemporal_store(a0, (f32x4*)(o));
        __builtin_nontemporal_store(a1, (f32x4*)(o + 4));
        __builtin_nontemporal_store(b0, (f32x4*)(o + OUT_C));
        __builtin_nontemporal_store(b1, (f32x4*)(o + OUT_C + 4));
        __builtin_nontemporal_store(c0, (f32x4*)(o + 2 * OUT_C));
        __builtin_nontemporal_store(c1, (f32x4*)(o + 2 * OUT_C + 4));
        __builtin_nontemporal_store(d0, (f32x4*)(o + 3 * OUT_C));
        __builtin_nontemporal_store(d1, (f32x4*)(o + 3 * OUT_C + 4));
    }
}

// ---------------------------------------------------------------------------
extern "C" void kernel_launch(void* const* d_in, const int* in_sizes, int n_in,
                              void* d_out, int out_size, void* d_ws, size_t ws_size,
                              hipStream_t stream) {
    const float* X      = (const float*)d_in[0];
    const float* W      = (const float*)d_in[1];
    const int*   A_rows = (const int*)d_in[2];
    const int*   A_cols = (const int*)d_in[3];
    const float* A_vals = (const float*)d_in[4];
    float* out = (float*)d_out;

    unsigned char* H8    = (unsigned char*)d_ws;                        // 12.8 MB
    float*         scale = (float*)((char*)d_ws + (size_t)NNODES * OUT_C); // 400 KB
    int*           rowptr = (int*)((char*)scale + (size_t)NNODES * sizeof(float));

    gemm_xwt<<<(NNODES + 127) / 128, 512, 0, stream>>>(X, W, H8, scale);
    build_rowptr<<<(NNODES + 1 + 255) / 256, 256, 0, stream>>>(A_rows, rowptr);
    spmm_rows<<<(NNODES + 15) / 16, 256, 0, stream>>>((const uint2*)H8, rowptr,
                                                      A_cols, A_vals, scale, out);
}

// Round 15
// 102.016 us; speedup vs baseline: 1.0378x; 1.0208x over previous
//
#include <hip/hip_runtime.h>
#include <hip/hip_bf16.h>

#define NNODES 100000
#define NEDGES 1600000
#define IN_C   256
#define OUT_C  128

typedef short bf16x8 __attribute__((ext_vector_type(8)));
typedef float f32x4  __attribute__((ext_vector_type(4)));

static __device__ __forceinline__ unsigned short f2bf(float f) {
    union { float f; unsigned u; } c; c.f = f;
    unsigned r = c.u + 0x7fffu + ((c.u >> 16) & 1u);   // round-to-nearest-even
    return (unsigned short)(r >> 16);
}

union BF8 { bf16x8 v; unsigned short s[8]; };

// ---------------------------------------------------------------------------
// GEMM: H8(biased uint8, row-major, per-row scale) = quant(X @ W^T).
// (R12-exact: W in 64KB swizzled LDS, X direct to A-frags, barrier-free
//  K-loop, per-row amax -> q+128 uint8.)
// ---------------------------------------------------------------------------
__global__ __launch_bounds__(512, 4) void gemm_xwt(const float* __restrict__ X,
                                                   const float* __restrict__ W,
                                                   unsigned char* __restrict__ H8,
                                                   float* __restrict__ scale) {
    __shared__ unsigned short Wsh[128 * 256];   // bf16 bits, [n][k], swizzled, 64KB

    const int tid  = threadIdx.x;
    const int lane = tid & 63;
    const int wid  = tid >> 6;                  // 0..7

#pragma unroll
    for (int p = 0; p < 16; ++p) {
        int idx = p * 512 + tid;                // 0..8191 float4 index
        int n   = idx >> 6;                     // 0..127
        int c4  = idx & 63;                     // float4 column
        float4 v = *(const float4*)(W + (size_t)n * IN_C + c4 * 4);
        int byte = (n * 512 + c4 * 8) ^ ((n & 7) << 4);
        *(ushort4*)((char*)Wsh + byte) =
            make_ushort4(f2bf(v.x), f2bf(v.y), f2bf(v.z), f2bf(v.w));
    }
    __syncthreads();

    const int r0   = blockIdx.x * 128 + wid * 16;
    int arow = r0 + (lane & 15);
    if (arow > NNODES - 1) arow = NNODES - 1;   // clamp (tail rows discarded)
    const float* xrow = X + (size_t)arow * IN_C + (lane >> 4) * 8;

    f32x4 acc[8] = {};
#pragma unroll
    for (int ks = 0; ks < 8; ++ks) {
        float4 a0 = *(const float4*)(xrow + ks * 32);
        float4 a1 = *(const float4*)(xrow + ks * 32 + 4);
        BF8 t;
        t.s[0] = f2bf(a0.x); t.s[1] = f2bf(a0.y); t.s[2] = f2bf(a0.z); t.s[3] = f2bf(a0.w);
        t.s[4] = f2bf(a1.x); t.s[5] = f2bf(a1.y); t.s[6] = f2bf(a1.z); t.s[7] = f2bf(a1.w);
        const int kb = ks * 64 + (lane >> 4) * 16;      // byte offset in W row
#pragma unroll
        for (int n8 = 0; n8 < 8; ++n8) {
            int nr   = n8 * 16 + (lane & 15);
            int byte = (nr * 512 + kb) ^ ((nr & 7) << 4);
            bf16x8 b = *(const bf16x8*)((const char*)Wsh + byte);
            acc[n8] = __builtin_amdgcn_mfma_f32_16x16x32_bf16(t.v, b, acc[n8],
                                                              0, 0, 0);
        }
    }

    // --- epilogue: per-row amax -> biased-uint8 quantize (row-major) ---
    float amax[4];
#pragma unroll
    for (int r = 0; r < 4; ++r) {
        float m = 0.f;
#pragma unroll
        for (int n8 = 0; n8 < 8; ++n8) m = fmaxf(m, fabsf(acc[n8][r]));
        amax[r] = m;
    }
#pragma unroll
    for (int d = 1; d < 16; d <<= 1)
#pragma unroll
        for (int r = 0; r < 4; ++r)
            amax[r] = fmaxf(amax[r], __shfl_xor(amax[r], d));

#pragma unroll
    for (int r = 0; r < 4; ++r) {
        int grow = r0 + (lane >> 4) * 4 + r;
        if (grow < NNODES) {
            float am  = amax[r];
            float inv = am > 0.f ? 127.f / am : 0.f;
            if ((lane & 15) == 0) scale[grow] = am * (1.f / 127.f);
#pragma unroll
            for (int n8 = 0; n8 < 8; ++n8) {
                float q = rintf(acc[n8][r] * inv);
                q = fminf(127.f, fmaxf(-127.f, q));
                H8[(size_t)grow * OUT_C + n8 * 16 + (lane & 15)] =
                    (unsigned char)((int)q + 128);
            }
        }
    }
}

// ---------------------------------------------------------------------------
// Fused prep: blocks [0, 392) build rowptr (binary search in sorted A_rows);
// blocks [392, 392+6250) fold ev[e] = vals[e] * scale[cols[e]] (streaming,
// scale table is L2-resident). Removes the random scale gather from spmm.
// ---------------------------------------------------------------------------
#define RP_BLOCKS 392
#define EV_BLOCKS ((NEDGES + 255) / 256)

__global__ __launch_bounds__(256) void prep(const int* __restrict__ rows,
                                            const int* __restrict__ cols,
                                            const float* __restrict__ vals,
                                            const float* __restrict__ scale,
                                            int* __restrict__ rowptr,
                                            float* __restrict__ ev) {
    if (blockIdx.x < RP_BLOCKS) {
        int r = blockIdx.x * 256 + threadIdx.x;
        if (r > NNODES) return;
        int lo = 0, hi = NEDGES;
        while (lo < hi) {
            int mid = (lo + hi) >> 1;
            if (rows[mid] < r) lo = mid + 1; else hi = mid;
        }
        rowptr[r] = lo;
    } else {
        int e = (blockIdx.x - RP_BLOCKS) * 256 + threadIdx.x;
        if (e < NEDGES)
            ev[e] = vals[e] * scale[cols[e]];
    }
}

// ---------------------------------------------------------------------------
// SpMM: out[r,:] = sum_e ev[e] * H8[cols[e],:].
// 2-row pipeline (best measured) with DIRECT-LOAD BROADCAST: no shfl, no
// preload — each 16-lane subgroup g loads cols[k+g]/ev[k+g] directly (same
// address within subgroup -> HW broadcast; affine addresses -> hoistable),
// then gathers H2[c*16+cg]. 2x unrolled -> 4 gathers in flight. Biased-uint8
// unpack; exact -128*sum(w) correction after the cross-group reduce.
// ---------------------------------------------------------------------------
static __device__ __forceinline__ void fma8(float acc[8], float* sw,
                                            uint2 u, float v) {
    *sw += v;
    acc[0] += v * (float)( u.x        & 0xffu);
    acc[1] += v * (float)((u.x >>  8) & 0xffu);
    acc[2] += v * (float)((u.x >> 16) & 0xffu);
    acc[3] += v * (float)( u.x >> 24);
    acc[4] += v * (float)( u.y        & 0xffu);
    acc[5] += v * (float)((u.y >>  8) & 0xffu);
    acc[6] += v * (float)((u.y >> 16) & 0xffu);
    acc[7] += v * (float)( u.y >> 24);
}

__global__ __launch_bounds__(256) void spmm_rows(const uint2* __restrict__ H2,
                                                 const int* __restrict__ rowptr,
                                                 const int* __restrict__ cols,
                                                 const float* __restrict__ ev,
                                                 float* __restrict__ out) {
    const int wid  = threadIdx.x >> 6;
    const int lane = threadIdx.x & 63;
    const int g    = lane >> 4;      // edge subgroup 0..3
    const int cg   = lane & 15;      // channel group: channels cg*8 .. cg*8+7

    const int rowA = (blockIdx.x * 4 + wid) * 2;   // rowB = rowA + 1
    const int sA = rowptr[rowA];
    const int eA = rowptr[rowA + 1];
    const int eB = rowptr[rowA + 2];

    float accA[8], accB[8];
#pragma unroll
    for (int t = 0; t < 8; ++t) { accA[t] = 0.f; accB[t] = 0.f; }
    float swA = 0.f, swB = 0.f;

    int kA = sA, kB = eA;           // group-base edge indices (uniform)
    while (kA < eA || kB < eB) {
        const bool dA0 = kA + g     < eA, dA1 = kA + 4 + g < eA;
        const bool dB0 = kB + g     < eB, dB1 = kB + 4 + g < eB;

        int   cA0, cA1, cB0, cB1;
        float vA0, vA1, vB0, vB1;
        uint2 uA0, uA1, uB0, uB1;
        // broadcast loads (affine addresses, subgroup-uniform -> HW broadcast)
        if (dA0) { cA0 = cols[kA + g];     vA0 = ev[kA + g]; }
        if (dB0) { cB0 = cols[kB + g];     vB0 = ev[kB + g]; }
        if (dA1) { cA1 = cols[kA + 4 + g]; vA1 = ev[kA + 4 + g]; }
        if (dB1) { cB1 = cols[kB + 4 + g]; vB1 = ev[kB + 4 + g]; }
        // gathers back-to-back
        if (dA0) uA0 = H2[(size_t)cA0 * 16 + cg];
        if (dB0) uB0 = H2[(size_t)cB0 * 16 + cg];
        if (dA1) uA1 = H2[(size_t)cA1 * 16 + cg];
        if (dB1) uB1 = H2[(size_t)cB1 * 16 + cg];
        // consume in issue order
        if (dA0) fma8(accA, &swA, uA0, vA0);
        if (dB0) fma8(accB, &swB, uB0, vB0);
        if (dA1) fma8(accA, &swA, uA1, vA1);
        if (dB1) fma8(accB, &swB, uB1, vB1);

        kA += 8; kB += 8;
    }

    // reduce across the 4 edge subgroups, then exact bias correction
#pragma unroll
    for (int t = 0; t < 8; ++t) {
        accA[t] += __shfl_xor(accA[t], 16);
        accA[t] += __shfl_xor(accA[t], 32);
        accB[t] += __shfl_xor(accB[t], 16);
        accB[t] += __shfl_xor(accB[t], 32);
    }
    swA += __shfl_xor(swA, 16); swA += __shfl_xor(swA, 32);
    swB += __shfl_xor(swB, 16); swB += __shfl_xor(swB, 32);

    if (lane < 16) {
        const float bA = 128.f * swA, bB = 128.f * swB;
        f32x4 a0 = { accA[0] - bA, accA[1] - bA, accA[2] - bA, accA[3] - bA };
        f32x4 a1 = { accA[4] - bA, accA[5] - bA, accA[6] - bA, accA[7] - bA };
        f32x4 b0 = { accB[0] - bB, accB[1] - bB, accB[2] - bB, accB[3] - bB };
        f32x4 b1 = { accB[4] - bB, accB[5] - bB, accB[6] - bB, accB[7] - bB };
        __builtin_nontemporal_store(a0, (f32x4*)(out + (size_t)rowA * OUT_C + cg * 8));
        __builtin_nontemporal_store(a1, (f32x4*)(out + (size_t)rowA * OUT_C + cg * 8 + 4));
        __builtin_nontemporal_store(b0, (f32x4*)(out + (size_t)(rowA + 1) * OUT_C + cg * 8));
        __builtin_nontemporal_store(b1, (f32x4*)(out + (size_t)(rowA + 1) * OUT_C + cg * 8 + 4));
    }
}

// ---------------------------------------------------------------------------
extern "C" void kernel_launch(void* const* d_in, const int* in_sizes, int n_in,
                              void* d_out, int out_size, void* d_ws, size_t ws_size,
                              hipStream_t stream) {
    const float* X      = (const float*)d_in[0];
    const float* W      = (const float*)d_in[1];
    const int*   A_rows = (const int*)d_in[2];
    const int*   A_cols = (const int*)d_in[3];
    const float* A_vals = (const float*)d_in[4];
    float* out = (float*)d_out;

    unsigned char* H8     = (unsigned char*)d_ws;                          // 12.8 MB
    float*         scale  = (float*)((char*)d_ws + (size_t)NNODES * OUT_C); // 400 KB
    int*           rowptr = (int*)((char*)scale + (size_t)NNODES * sizeof(float));
    float*         ev     = (float*)((char*)rowptr + (size_t)(NNODES + 2) * sizeof(int));

    gemm_xwt<<<(NNODES + 127) / 128, 512, 0, stream>>>(X, W, H8, scale);
    prep<<<RP_BLOCKS + EV_BLOCKS, 256, 0, stream>>>(A_rows, A_cols, A_vals,
                                                    scale, rowptr, ev);
    spmm_rows<<<(NNODES + 7) / 8, 256, 0, stream>>>((const uint2*)H8, rowptr,
                                                    A_cols, ev, out);
}